// Round 8
// baseline (487.583 us; speedup 1.0000x reference)
//
#include <hip/hip_runtime.h>
#include <hip/hip_bf16.h>

#define E_ 1024
#define L_ 25
#define S_ 64
#define C_ 128
#define H_ 512
#define NEXP_ 8

// workspace float offsets
#define OFF_W     0         // 128 (wk @ bq fold, for mw[t])
#define OFF_PEDOT 128       // 64*64 -> 4224
#define OFF_B1P   4224      // 8*512 -> 8320
#define OFF_GTF   8320      // 16384 bf16 (G frags) = 8192 fl -> 16512
#define OFF_WVTF  16512     // 16384 bf16 (Wv^T frags) -> 24704
#define OFF_TGF   24704     // 2048 bf16 (to_grid A-frags) = 1024 fl -> 25728
#define OFF_W1S   25728     // 524288 bf16 = 262144 fl -> 287872
#define OFF_W2S   287872    // 524288 bf16 -> 550016
#define OFF_NOUT  550016    // 1024*64*128 bf16 = 4194304 fl -> 4744320 (~19 MB)

typedef float floatx4 __attribute__((ext_vector_type(4)));
typedef __bf16 bf16x8 __attribute__((ext_vector_type(8)));
typedef __bf16 bf16x4 __attribute__((ext_vector_type(4)));

// ---------------- prepAll: every weight transform in ONE launch ----------------
// blocks [0,2048): w1s A-frags (LN-gain folded)
// blocks [2048,4096): w2s A-frags
// blocks [4096,4160): gtf B-frags via direct dot (G = Wq Wk^T, no intermediate)
// blocks [4160,4224): wvtf B-frags
// block 4224: tgf A-frags + w-fold + pedot
// blocks [4225,4289): b1p = elnb @ w1 + b1
__global__ void prepAll(const float* __restrict__ wq, const float* __restrict__ bq,
                        const float* __restrict__ wk, const float* __restrict__ wv,
                        const float* __restrict__ tg, const float* __restrict__ pe,
                        const float* __restrict__ elng, const float* __restrict__ elnb,
                        const float* __restrict__ w1, const float* __restrict__ b1,
                        const float* __restrict__ w2,
                        __hip_bfloat16* __restrict__ w1s, __hip_bfloat16* __restrict__ w2s,
                        __hip_bfloat16* __restrict__ gtf, __hip_bfloat16* __restrict__ wvtf,
                        __hip_bfloat16* __restrict__ tgf, float* __restrict__ ws) {
    const int b = blockIdx.x, tid = threadIdx.x;
    if (b < 2048) {
        int idx = b * 256 + tid;          // < 524288
        int f = idx >> 9, r = idx & 511;
        int lane = r >> 3, j = r & 7;
        int kt = f & 3, htg = (f >> 2) & 31, ex = f >> 7;
        int c = kt * 32 + (lane >> 4) * 8 + j;
        int h = htg * 16 + (lane & 15);
        w1s[idx] = __float2bfloat16(elng[ex * 128 + c] * w1[ex * 65536 + c * 512 + h]);
    } else if (b < 4096) {
        int i2 = (b - 2048) * 256 + tid;  // < 524288
        int f = i2 >> 9, r = i2 & 511;
        int lane = r >> 3, j = r & 7;
        int ktg = f & 15, ctg = (f >> 4) & 7, ex = f >> 7;
        int h = ktg * 32 + (lane >> 4) * 8 + j;
        int c = ctg * 16 + (lane & 15);
        w2s[i2] = __float2bfloat16(w2[ex * 65536 + h * 128 + c]);
    } else if (b < 4160) {
        int i2 = (b - 4096) * 256 + tid;  // < 16384
        int f = i2 >> 9, r = i2 & 511;
        int lane = r >> 3, j = r & 7;
        int kt = f & 3, Nt = f >> 2;
        int k = kt * 32 + (lane >> 4) * 8 + j;   // row of wq
        int n = Nt * 16 + (lane & 15);           // row of wk
        float acc = 0.f;
        const float* ra = wq + k * C_;
        const float* rb = wk + n * C_;
        for (int c = 0; c < C_; ++c) acc += ra[c] * rb[c];
        gtf[i2] = __float2bfloat16(acc);         // Brow[j][c] = G[c][j]
    } else if (b < 4224) {
        int i2 = (b - 4160) * 256 + tid;  // < 16384
        int f = i2 >> 9, r = i2 & 511;
        int lane = r >> 3, j = r & 7;
        int kt = f & 3, Nt = f >> 2;
        int k = kt * 32 + (lane >> 4) * 8 + j;
        int n = Nt * 16 + (lane & 15);
        wvtf[i2] = __float2bfloat16(wv[k * 128 + n]);   // Brow[c][j] = wv[j][c]
    } else if (b == 4224) {
        for (int i3 = tid; i3 < 2048; i3 += 256) {
            int f = i3 >> 9, r = i3 & 511;
            int lane = r >> 3, j = r & 7;
            int m = f * 16 + (lane & 15);
            int k = (lane >> 4) * 8 + j;
            tgf[i3] = (k < 25) ? __float2bfloat16(tg[m * 25 + k]) : __float2bfloat16(0.f);
        }
        if (tid < 128) {   // w[j] = wk_row_j . bq
            float acc = 0.f; const float* r = wk + tid * C_;
            for (int c = 0; c < C_; ++c) acc += r[c] * bq[c];
            ws[OFF_W + tid] = acc;
        }
        for (int idx = tid; idx < 64 * 64; idx += 256) {
            int s = idx >> 6, t = idx & 63;
            ws[OFF_PEDOT + idx] = pe[s*3]*pe[t*3] + pe[s*3+1]*pe[t*3+1] + pe[s*3+2]*pe[t*3+2];
        }
    } else {
        __shared__ float red[256];
        int bb = b - 4225;               // 0..63
        int i = bb >> 3, seg = bb & 7;
        int hl = tid & 63, part = tid >> 6;
        int h = seg * 64 + hl;
        const float* wcol = w1 + i * 65536 + h;
        float acc = 0.f;
        for (int c = part * 32; c < part * 32 + 32; ++c)
            acc += elnb[i * 128 + c] * wcol[c * 512];
        red[tid] = acc;
        __syncthreads();
        if (part == 0)
            ws[OFF_B1P + i * 512 + h] = red[hl] + red[hl + 64] + red[hl + 128] + red[hl + 192]
                                      + b1[i * 512 + h];
    }
}

// ---------------- kernA: fused grid-proj + LN + MFMA attention + l0 branch ----------------
// Conventions (verified): D[m][n] = sum_k A[m][k]*Brow[n][k]
//   A-frag: row lane&15, bytes kt*64 + quad*16 of a row-major K-contiguous row
//   B-frag: same pattern on Brow;  C/D: n = Ntbase + col, m = Mtbase + quad*4 + reg
__global__ __launch_bounds__(256) void kernA(
        const float* __restrict__ message, const float* __restrict__ ln1g,
        const float* __restrict__ ln1b, const float* __restrict__ bv,
        const float* __restrict__ ws_ro,
        const __hip_bfloat16* __restrict__ gtf, const __hip_bfloat16* __restrict__ wvtf,
        const __hip_bfloat16* __restrict__ tgf,
        const float* __restrict__ nlg, const float* __restrict__ nlb,
        const float* __restrict__ fcw, const float* __restrict__ fcb,
        __hip_bfloat16* __restrict__ nout, float* __restrict__ out) {
    __shared__ __align__(16) char sA[64 * 272];    // m rows [s][c]
    __shared__ __align__(16) char sB[64 * 272];    // (msg fp32 stage) -> z -> p -> out rows
    __shared__ __align__(16) char sC[128 * 144];   // (msgT bf16) -> sc fp32 [64][68] -> vT rows
    __shared__ __align__(16) float sStP[512];
    __shared__ __align__(16) float sSt2[128];
    __shared__ float sMw[64];
    __shared__ float sMsg0[128];                   // l0 branch input

    const int e = blockIdx.x, tid = threadIdx.x;
    const int w = tid >> 6, lane = tid & 63, quad = lane >> 4, col = lane & 15;

    // ---- 0a. stage msg fp32 (coalesced) into sB overlay; msg row 0 for l0 ----
    float* sMsgF = (float*)sB;
    for (int i = tid; i < 3200; i += 256) sMsgF[i] = message[(size_t)e * 3200 + i];
    if (tid < 128) sMsg0[tid] = message[(size_t)e * 3200 + tid];
    __syncthreads();   // S0a

    // ---- 0b. transpose+cvt+pad: msgT[c][l] bf16, row stride 80 B, l=25..31 zero ----
    char* sMt = sC;
    for (int i = tid; i < 4096; i += 256) {
        int c = i >> 5, l = i & 31;
        float v = (l < 25) ? sMsgF[l * 128 + c] : 0.f;
        *(__hip_bfloat16*)(sMt + c * 80 + l * 2) = __float2bfloat16(v);
    }
    __syncthreads();   // S0b

    // ---- 0c. g = to_grid @ msgT (K=32 MFMA); fused LN stats from registers ----
    floatx4 accG[4][2];
    {
        #pragma unroll
        for (int mt = 0; mt < 4; ++mt) { accG[mt][0] = (floatx4)0.f; accG[mt][1] = (floatx4)0.f; }
        bf16x8 a[4], b[2];
        #pragma unroll
        for (int mt = 0; mt < 4; ++mt) a[mt] = *(const bf16x8*)(tgf + mt * 512 + lane * 8);
        #pragma unroll
        for (int nt = 0; nt < 2; ++nt)
            b[nt] = *(const bf16x8*)(sMt + ((2 * w + nt) * 16 + col) * 80 + quad * 16);
        #pragma unroll
        for (int mt = 0; mt < 4; ++mt)
            #pragma unroll
            for (int nt = 0; nt < 2; ++nt)
                accG[mt][nt] = __builtin_amdgcn_mfma_f32_16x16x32_bf16(a[mt], b[nt], accG[mt][nt], 0, 0, 0);
    }
    #pragma unroll
    for (int mt = 0; mt < 4; ++mt)
        #pragma unroll
        for (int reg = 0; reg < 4; ++reg) {
            float v0 = accG[mt][0][reg], v1 = accG[mt][1][reg];
            float sm = v0 + v1, sq = v0 * v0 + v1 * v1;
            #pragma unroll
            for (int m = 1; m < 16; m <<= 1) {
                sm += __shfl_xor(sm, m, 64);
                sq += __shfl_xor(sq, m, 64);
            }
            if (col == 0) {
                int s = mt * 16 + quad * 4 + reg;
                sStP[(s * 4 + w) * 2]     = sm;
                sStP[(s * 4 + w) * 2 + 1] = sq;
            }
        }
    __syncthreads();   // Sg1
    if (tid < 64) {
        float sm = 0.f, sq = 0.f;
        #pragma unroll
        for (int k = 0; k < 4; ++k) {
            sm += sStP[(tid * 4 + k) * 2];
            sq += sStP[(tid * 4 + k) * 2 + 1];
        }
        float mean = sm * (1.f / 128.f);
        float rstd = rsqrtf(sq * (1.f / 128.f) - mean * mean + 1e-5f);
        sSt2[tid * 2] = mean; sSt2[tid * 2 + 1] = rstd;
    }
    __syncthreads();   // Sg2
    {
        float g1[2], b1v[2];
        #pragma unroll
        for (int nt = 0; nt < 2; ++nt) {
            int c = (2 * w + nt) * 16 + col;
            g1[nt] = ln1g[c]; b1v[nt] = ln1b[c];
        }
        #pragma unroll
        for (int mt = 0; mt < 4; ++mt)
            #pragma unroll
            for (int reg = 0; reg < 4; ++reg) {
                int s = mt * 16 + quad * 4 + reg;
                float mean = sSt2[s * 2], rstd = sSt2[s * 2 + 1];
                #pragma unroll
                for (int nt = 0; nt < 2; ++nt) {
                    int c = (2 * w + nt) * 16 + col;
                    ((__hip_bfloat16*)(sA + s * 272))[c] =
                        __float2bfloat16((accG[mt][nt][reg] - mean) * rstd * g1[nt] + b1v[nt]);
                }
            }
    }
    __syncthreads();   // S1 (m rows ready)

    // ---- 2. mw[t] = m_t . w ----
    {
        int t = tid >> 2, part = tid & 3;
        const __hip_bfloat16* mr = (const __hip_bfloat16*)(sA + t * 272) + part * 32;
        const float* wv_ = ws_ro + OFF_W + part * 32;
        float acc = 0.f;
        #pragma unroll
        for (int k = 0; k < 32; ++k) acc += __bfloat162float(mr[k]) * wv_[k];
        acc += __shfl_xor(acc, 1, 64);
        acc += __shfl_xor(acc, 2, 64);
        if (part == 0) sMw[t] = acc;
    }

    // ---- 3. z = m @ G (B-frags) ----
    {
        floatx4 accZ[4][2];
        #pragma unroll
        for (int mt = 0; mt < 4; ++mt) { accZ[mt][0] = (floatx4)0.f; accZ[mt][1] = (floatx4)0.f; }
        #pragma unroll
        for (int kt = 0; kt < 4; ++kt) {
            bf16x8 a[4], b[2];
            #pragma unroll
            for (int mt = 0; mt < 4; ++mt)
                a[mt] = *(const bf16x8*)(sA + (mt * 16 + col) * 272 + kt * 64 + quad * 16);
            #pragma unroll
            for (int nt = 0; nt < 2; ++nt)
                b[nt] = *(const bf16x8*)(gtf + ((2 * w + nt) * 4 + kt) * 512 + lane * 8);
            #pragma unroll
            for (int mt = 0; mt < 4; ++mt)
                #pragma unroll
                for (int nt = 0; nt < 2; ++nt)
                    accZ[mt][nt] = __builtin_amdgcn_mfma_f32_16x16x32_bf16(a[mt], b[nt], accZ[mt][nt], 0, 0, 0);
        }
        #pragma unroll
        for (int mt = 0; mt < 4; ++mt)
            #pragma unroll
            for (int nt = 0; nt < 2; ++nt) {
                int j = (2 * w + nt) * 16 + col;
                #pragma unroll
                for (int reg = 0; reg < 4; ++reg)
                    ((__hip_bfloat16*)(sB + (mt * 16 + quad * 4 + reg) * 272))[j] =
                        __float2bfloat16(accZ[mt][nt][reg]);
            }
    }
    __syncthreads();   // S2

    // ---- 4. sc = z @ m^T ----
    {
        floatx4 accS[4];
        #pragma unroll
        for (int mt = 0; mt < 4; ++mt) accS[mt] = (floatx4)0.f;
        #pragma unroll
        for (int kt = 0; kt < 4; ++kt) {
            bf16x8 a[4];
            #pragma unroll
            for (int mt = 0; mt < 4; ++mt)
                a[mt] = *(const bf16x8*)(sB + (mt * 16 + col) * 272 + kt * 64 + quad * 16);
            bf16x8 b = *(const bf16x8*)(sA + (w * 16 + col) * 272 + kt * 64 + quad * 16);
            #pragma unroll
            for (int mt = 0; mt < 4; ++mt)
                accS[mt] = __builtin_amdgcn_mfma_f32_16x16x32_bf16(a[mt], b, accS[mt], 0, 0, 0);
        }
        float* sc = (float*)sC;
        #pragma unroll
        for (int mt = 0; mt < 4; ++mt)
            #pragma unroll
            for (int reg = 0; reg < 4; ++reg)
                sc[(mt * 16 + quad * 4 + reg) * 68 + w * 16 + col] = accS[mt][reg];
    }
    __syncthreads();   // S3

    // ---- 5. softmax rows -> p rows bf16 ----
    {
        const float scale = 0.08737040566610379f;   // 1/sqrt(131)
        const float* sc = (const float*)sC;
        const float* pd = ws_ro + OFF_PEDOT;
        for (int r = 0; r < 16; ++r) {
            int s = w * 16 + r;
            float x = sc[s * 68 + lane] + sMw[lane] + pd[s * 64 + lane];
            float mx = x;
            #pragma unroll
            for (int m = 1; m < 64; m <<= 1) mx = fmaxf(mx, __shfl_xor(mx, m, 64));
            float p = __expf((x - mx) * scale);
            float sm = p;
            #pragma unroll
            for (int m = 1; m < 64; m <<= 1) sm += __shfl_xor(sm, m, 64);
            float rs = __builtin_amdgcn_rcpf(sm);
            ((__hip_bfloat16*)(sB + s * 272))[lane] = __float2bfloat16(p * rs);
        }
    }
    __syncthreads();   // S4

    // ---- 6. v = m @ Wv^T + bv -> vT rows [c][t] ----
    {
        floatx4 accV[4][2];
        #pragma unroll
        for (int mt = 0; mt < 4; ++mt) { accV[mt][0] = (floatx4)0.f; accV[mt][1] = (floatx4)0.f; }
        #pragma unroll
        for (int kt = 0; kt < 4; ++kt) {
            bf16x8 a[4], b[2];
            #pragma unroll
            for (int mt = 0; mt < 4; ++mt)
                a[mt] = *(const bf16x8*)(sA + (mt * 16 + col) * 272 + kt * 64 + quad * 16);
            #pragma unroll
            for (int nt = 0; nt < 2; ++nt)
                b[nt] = *(const bf16x8*)(wvtf + ((2 * w + nt) * 4 + kt) * 512 + lane * 8);
            #pragma unroll
            for (int mt = 0; mt < 4; ++mt)
                #pragma unroll
                for (int nt = 0; nt < 2; ++nt)
                    accV[mt][nt] = __builtin_amdgcn_mfma_f32_16x16x32_bf16(a[mt], b[nt], accV[mt][nt], 0, 0, 0);
        }
        #pragma unroll
        for (int nt = 0; nt < 2; ++nt) {
            int c = (2 * w + nt) * 16 + col;
            float bvv = bv[c];
            #pragma unroll
            for (int mt = 0; mt < 4; ++mt) {
                bf16x4 pk;
                #pragma unroll
                for (int reg = 0; reg < 4; ++reg)
                    pk[reg] = (__bf16)(accV[mt][nt][reg] + bvv);
                *(bf16x4*)(sC + c * 144 + (mt * 16 + quad * 4) * 2) = pk;
            }
        }
    }
    __syncthreads();   // S5

    // ---- 7. out = p @ vT ----
    floatx4 accO[4][2];
    #pragma unroll
    for (int mt = 0; mt < 4; ++mt) { accO[mt][0] = (floatx4)0.f; accO[mt][1] = (floatx4)0.f; }
    #pragma unroll
    for (int kt = 0; kt < 2; ++kt) {
        bf16x8 a[4], b[2];
        #pragma unroll
        for (int mt = 0; mt < 4; ++mt)
            a[mt] = *(const bf16x8*)(sB + (mt * 16 + col) * 272 + kt * 64 + quad * 16);
        #pragma unroll
        for (int nt = 0; nt < 2; ++nt)
            b[nt] = *(const bf16x8*)(sC + ((2 * w + nt) * 16 + col) * 144 + kt * 64 + quad * 16);
        #pragma unroll
        for (int mt = 0; mt < 4; ++mt)
            #pragma unroll
            for (int nt = 0; nt < 2; ++nt)
                accO[mt][nt] = __builtin_amdgcn_mfma_f32_16x16x32_bf16(a[mt], b[nt], accO[mt][nt], 0, 0, 0);
    }

    // ---- 8. LN partials ----
    #pragma unroll
    for (int mt = 0; mt < 4; ++mt)
        #pragma unroll
        for (int reg = 0; reg < 4; ++reg) {
            float v0 = accO[mt][0][reg], v1 = accO[mt][1][reg];
            float sm = v0 + v1, sq = v0 * v0 + v1 * v1;
            #pragma unroll
            for (int m = 1; m < 16; m <<= 1) {
                sm += __shfl_xor(sm, m, 64);
                sq += __shfl_xor(sq, m, 64);
            }
            if (col == 0) {
                int s = mt * 16 + quad * 4 + reg;
                sStP[(s * 4 + w) * 2]     = sm;
                sStP[(s * 4 + w) * 2 + 1] = sq;
            }
        }
    __syncthreads();   // S6
    if (tid < 64) {
        float sm = 0.f, sq = 0.f;
        #pragma unroll
        for (int k = 0; k < 4; ++k) {
            sm += sStP[(tid * 4 + k) * 2];
            sq += sStP[(tid * 4 + k) * 2 + 1];
        }
        float mean = sm * (1.f / 128.f);
        float rstd = rsqrtf(sq * (1.f / 128.f) - mean * mean + 1e-5f);
        sSt2[tid * 2] = mean; sSt2[tid * 2 + 1] = rstd;
    }
    __syncthreads();   // S7

    // ---- 9. normalize -> out rows bf16 ----
    #pragma unroll
    for (int mt = 0; mt < 4; ++mt)
        #pragma unroll
        for (int reg = 0; reg < 4; ++reg) {
            int s = mt * 16 + quad * 4 + reg;
            float mean = sSt2[s * 2], rstd = sSt2[s * 2 + 1];
            #pragma unroll
            for (int nt = 0; nt < 2; ++nt) {
                int c = (2 * w + nt) * 16 + col;
                ((__hip_bfloat16*)(sB + s * 272))[c] =
                    __float2bfloat16((accO[mt][nt][reg] - mean) * rstd);
            }
        }
    __syncthreads();   // S8

    // ---- 10. coalesced store nout ----
    for (int i = tid; i < 1024; i += 256) {
        int row = i >> 4, c16 = i & 15;
        bf16x8 v = *(const bf16x8*)(sB + row * 272 + c16 * 16);
        *(bf16x8*)(nout + (size_t)e * 8192 + row * 128 + c16 * 8) = v;
    }

    // ---- 11. l0 branch: LN -> Linear -> SiLU -> out row 0 ----
    if (tid < 64) {
        float x0 = sMsg0[tid], x1 = sMsg0[tid + 64];
        float sm = x0 + x1, sq = x0 * x0 + x1 * x1;
        #pragma unroll
        for (int m = 1; m < 64; m <<= 1) {
            sm += __shfl_xor(sm, m, 64);
            sq += __shfl_xor(sq, m, 64);
        }
        float mean = sm * (1.f / 128.f);
        float rstd = rsqrtf(sq * (1.f / 128.f) - mean * mean + 1e-5f);
        sMsg0[tid]      = (x0 - mean) * rstd * nlg[tid]      + nlb[tid];
        sMsg0[tid + 64] = (x1 - mean) * rstd * nlg[tid + 64] + nlb[tid + 64];
    }
    __syncthreads();   // S9
    {
        int c = tid & 127, jh = tid >> 7;
        float acc = 0.f;
        for (int j = jh * 64; j < jh * 64 + 64; ++j)
            acc += sMsg0[j] * fcw[j * 128 + c];
        sStP[tid] = acc;
    }
    __syncthreads();   // S10
    if (tid < 128) {
        float o = fcb[tid] + sStP[tid] + sStP[tid + 128];
        out[(size_t)e * 3200 + tid] = o * __builtin_amdgcn_rcpf(1.f + __expf(-o));
    }
}

// ---------------- kernC: 1 edge/block, X-frags hoisted in VGPRs ----------------
__global__ __launch_bounds__(256, 2) void kernC(
        const __hip_bfloat16* __restrict__ nout_ro, const float* __restrict__ gate,
        const __hip_bfloat16* __restrict__ w1s, const __hip_bfloat16* __restrict__ w2s,
        const float* __restrict__ b1p, const float* __restrict__ b2,
        const float* __restrict__ fg, float* __restrict__ out) {

    __shared__ __align__(16) char smem[64 * 528];   // sS (64*272) / epilogue sAcc (64*132 fl)
    __shared__ float sGB2[128];
    char* sSb = smem;
    float* sAcc = (float*)smem;

    const int e = blockIdx.x;
    const int tid = threadIdx.x;
    const int w = tid >> 6, lane = tid & 63;
    const int quad = lane >> 4, col = lane & 15;
    const int htB = (w >> 1) * 4;      // M-tile base (h/4 in matmul1, c/4 in matmul2)
    const int stB = (w & 1) * 2;       // N-tile base (s)

    // ---- hoist X B-frags straight from global (loop-invariant, 32 VGPRs) ----
    bf16x8 Xf[2][4];
    #pragma unroll
    for (int nt = 0; nt < 2; ++nt)
        #pragma unroll
        for (int kt = 0; kt < 4; ++kt)
            Xf[nt][kt] = *(const bf16x8*)(nout_ro +
                ((size_t)e * 64 + (stB + nt) * 16 + col) * 128 + kt * 32 + quad * 8);

    if (tid < 128) {   // gate-weighted b2
        float s = 0.f;
        #pragma unroll
        for (int ex = 0; ex < 8; ++ex) s += gate[e * 8 + ex] * b2[ex * 128 + tid];
        sGB2[tid] = s;
    }

    floatx4 accT[4][2];
    #pragma unroll
    for (int m = 0; m < 4; ++m) { accT[m][0] = (floatx4)0.f; accT[m][1] = (floatx4)0.f; }

    for (int it = 0; it < 32; ++it) {
        const int ex = it >> 2, hb = it & 3;
        const float gv = gate[e * 8 + ex];

        // ---- matmul1 + silu, streaming a1 per mt ----
        #pragma unroll
        for (int mt = 0; mt < 4; ++mt) {
            bf16x8 a1[4];
            #pragma unroll
            for (int kt = 0; kt < 4; ++kt)
                a1[kt] = *(const bf16x8*)(w1s + (size_t)((ex*32 + hb*8 + htB + mt)*4 + kt)*512 + lane*8);
            float4 bias = *(const float4*)(b1p + ex * 512 + hb * 128 + (htB + mt) * 16 + quad * 4);
            floatx4 accP[2];
            #pragma unroll
            for (int nt = 0; nt < 2; ++nt) {
                accP[nt][0] = bias.x; accP[nt][1] = bias.y;
                accP[nt][2] = bias.z; accP[nt][3] = bias.w;
            }
            #pragma unroll
            for (int kt = 0; kt < 4; ++kt)
                #pragma unroll
                for (int nt = 0; nt < 2; ++nt)
                    accP[nt] = __builtin_amdgcn_mfma_f32_16x16x32_bf16(a1[kt], Xf[nt][kt], accP[nt], 0, 0, 0);
            int hl = (htB + mt) * 16 + quad * 4;
            #pragma unroll
            for (int nt = 0; nt < 2; ++nt) {
                int nl = (stB + nt) * 16 + col;
                bf16x4 sv;
                #pragma unroll
                for (int r = 0; r < 4; ++r) {
                    float p = accP[nt][r];
                    sv[r] = (__bf16)(gv * p * __builtin_amdgcn_rcpf(1.f + __expf(-p)));
                }
                *(bf16x4*)(sSb + nl * 272 + hl * 2) = sv;
            }
        }
        __syncthreads();

        // ---- matmul2: hoist S B-frags, stream a2 per mt ----
        bf16x8 Sf[2][4];
        #pragma unroll
        for (int nt = 0; nt < 2; ++nt)
            #pragma unroll
            for (int kt = 0; kt < 4; ++kt)
                Sf[nt][kt] = *(const bf16x8*)(sSb + ((stB + nt) * 16 + col) * 272 + kt * 64 + quad * 16);
        #pragma unroll
        for (int mt = 0; mt < 4; ++mt) {
            bf16x8 a2[4];
            #pragma unroll
            for (int kt = 0; kt < 4; ++kt)
                a2[kt] = *(const bf16x8*)(w2s + (size_t)((ex*8 + htB + mt)*16 + hb*4 + kt)*512 + lane*8);
            #pragma unroll
            for (int kt = 0; kt < 4; ++kt)
                #pragma unroll
                for (int nt = 0; nt < 2; ++nt)
                    accT[mt][nt] = __builtin_amdgcn_mfma_f32_16x16x32_bf16(a2[kt], Sf[nt][kt], accT[mt][nt], 0, 0, 0);
        }
        __syncthreads();
    }

    // ---- epilogue: acc -> sAcc, then out[l][c] = sum_s fg[l][s] * acc[s][c] ----
    #pragma unroll
    for (int mt = 0; mt < 4; ++mt) {
        int c = (htB + mt) * 16 + quad * 4;
        float4 gb = *(const float4*)(&sGB2[c]);
        #pragma unroll
        for (int nt = 0; nt < 2; ++nt) {
            int nl = (stB + nt) * 16 + col;
            float4 v;
            v.x = accT[mt][nt][0] + gb.x;
            v.y = accT[mt][nt][1] + gb.y;
            v.z = accT[mt][nt][2] + gb.z;
            v.w = accT[mt][nt][3] + gb.w;
            *(float4*)(sAcc + nl * 132 + c) = v;
        }
    }
    __syncthreads();
    for (int idx = tid; idx < 768; idx += 256) {
        int l = 1 + (idx >> 5);
        int c4 = (idx & 31) * 4;
        float4 a4 = {0.f, 0.f, 0.f, 0.f};
        const float* fgr = fg + l * 64;
        for (int s = 0; s < 64; ++s) {
            float f = fgr[s];
            const float* row = sAcc + s * 132 + c4;
            a4.x += f * row[0]; a4.y += f * row[1]; a4.z += f * row[2]; a4.w += f * row[3];
        }
        *(float4*)(out + (size_t)e * 3200 + l * 128 + c4) = a4;
    }
}

extern "C" void kernel_launch(void* const* d_in, const int* in_sizes, int n_in,
                              void* d_out, int out_size, void* d_ws, size_t ws_size,
                              hipStream_t stream) {
    (void)in_sizes; (void)n_in; (void)out_size; (void)ws_size;
    const float* message = (const float*)d_in[0];
    const float* gate    = (const float*)d_in[1];
    // d_in[2] = batch (unused by reference math)
    const float* ln1g = (const float*)d_in[3];
    const float* ln1b = (const float*)d_in[4];
    const float* wq   = (const float*)d_in[5];
    const float* bq   = (const float*)d_in[6];
    const float* wk   = (const float*)d_in[7];
    const float* bk   = (const float*)d_in[8];
    (void)bk;   // cancels in softmax (row-constant)
    const float* wv   = (const float*)d_in[9];
    const float* bv   = (const float*)d_in[10];
    const float* nlg  = (const float*)d_in[11];
    const float* nlb  = (const float*)d_in[12];
    const float* fcw  = (const float*)d_in[13];
    const float* fcb  = (const float*)d_in[14];
    const float* elng = (const float*)d_in[15];
    const float* elnb = (const float*)d_in[16];
    const float* w1   = (const float*)d_in[17];
    const float* b1   = (const float*)d_in[18];
    const float* w2   = (const float*)d_in[19];
    const float* b2   = (const float*)d_in[20];
    const float* tg   = (const float*)d_in[21];
    const float* fg   = (const float*)d_in[22];
    const float* pe   = (const float*)d_in[23];
    float* ws  = (float*)d_ws;
    float* out = (float*)d_out;
    __hip_bfloat16* gtfp = (__hip_bfloat16*)(ws + OFF_GTF);
    __hip_bfloat16* wvtf = (__hip_bfloat16*)(ws + OFF_WVTF);
    __hip_bfloat16* tgf  = (__hip_bfloat16*)(ws + OFF_TGF);
    __hip_bfloat16* w1s  = (__hip_bfloat16*)(ws + OFF_W1S);
    __hip_bfloat16* w2s  = (__hip_bfloat16*)(ws + OFF_W2S);
    __hip_bfloat16* nout = (__hip_bfloat16*)(ws + OFF_NOUT);

    prepAll<<<dim3(4289), dim3(256), 0, stream>>>(wq, bq, wk, wv, tg, pe, elng, elnb,
                                                  w1, b1, w2, w1s, w2s, gtfp, wvtf, tgf, ws);
    kernA<<<dim3(E_), dim3(256), 0, stream>>>(message, ln1g, ln1b, bv, ws, gtfp, wvtf, tgf,
                                              nlg, nlb, fcw, fcb, nout, out);
    kernC<<<dim3(E_), dim3(256), 0, stream>>>(nout, gate, w1s, w2s,
                                              ws + OFF_B1P, b2, fg, out);
}

// Round 9
// 401.164 us; speedup vs baseline: 1.2154x; 1.2154x over previous
//
#include <hip/hip_runtime.h>
#include <hip/hip_bf16.h>

#define E_ 1024
#define L_ 25
#define S_ 64
#define C_ 128
#define H_ 512
#define NEXP_ 8

// workspace float offsets
#define OFF_W     0         // 128 (wk @ bq fold, for mw[t])
#define OFF_PEDOT 128       // 64*64 -> 4224
#define OFF_B1P   4224      // 8*512 -> 8320
#define OFF_GTF   8320      // 16384 bf16 (G frags) = 8192 fl -> 16512
#define OFF_WVTF  16512     // 16384 bf16 (Wv^T frags) -> 24704
#define OFF_TGF   24704     // 2048 bf16 (to_grid A-frags) = 1024 fl -> 25728
#define OFF_W1S   25728     // 524288 bf16 = 262144 fl -> 287872
#define OFF_W2S   287872    // 524288 bf16 -> 550016
#define OFF_NOUT  550016    // 1024*64*128 bf16 = 4194304 fl -> 4744320 (~19 MB)

typedef float floatx4 __attribute__((ext_vector_type(4)));
typedef __bf16 bf16x8 __attribute__((ext_vector_type(8)));
typedef __bf16 bf16x4 __attribute__((ext_vector_type(4)));

// ---------------- prepAll: every weight transform in ONE launch ----------------
__global__ void prepAll(const float* __restrict__ wq, const float* __restrict__ bq,
                        const float* __restrict__ wk, const float* __restrict__ wv,
                        const float* __restrict__ tg, const float* __restrict__ pe,
                        const float* __restrict__ elng, const float* __restrict__ elnb,
                        const float* __restrict__ w1, const float* __restrict__ b1,
                        const float* __restrict__ w2,
                        __hip_bfloat16* __restrict__ w1s, __hip_bfloat16* __restrict__ w2s,
                        __hip_bfloat16* __restrict__ gtf, __hip_bfloat16* __restrict__ wvtf,
                        __hip_bfloat16* __restrict__ tgf, float* __restrict__ ws) {
    const int b = blockIdx.x, tid = threadIdx.x;
    if (b < 2048) {
        int idx = b * 256 + tid;          // < 524288
        int f = idx >> 9, r = idx & 511;
        int lane = r >> 3, j = r & 7;
        int kt = f & 3, htg = (f >> 2) & 31, ex = f >> 7;
        int c = kt * 32 + (lane >> 4) * 8 + j;
        int h = htg * 16 + (lane & 15);
        w1s[idx] = __float2bfloat16(elng[ex * 128 + c] * w1[ex * 65536 + c * 512 + h]);
    } else if (b < 4096) {
        int i2 = (b - 2048) * 256 + tid;  // < 524288
        int f = i2 >> 9, r = i2 & 511;
        int lane = r >> 3, j = r & 7;
        int ktg = f & 15, ctg = (f >> 4) & 7, ex = f >> 7;
        int h = ktg * 32 + (lane >> 4) * 8 + j;
        int c = ctg * 16 + (lane & 15);
        w2s[i2] = __float2bfloat16(w2[ex * 65536 + h * 128 + c]);
    } else if (b < 4160) {
        int i2 = (b - 4096) * 256 + tid;  // < 16384
        int f = i2 >> 9, r = i2 & 511;
        int lane = r >> 3, j = r & 7;
        int kt = f & 3, Nt = f >> 2;
        int k = kt * 32 + (lane >> 4) * 8 + j;   // row of wq
        int n = Nt * 16 + (lane & 15);           // row of wk
        float acc = 0.f;
        const float* ra = wq + k * C_;
        const float* rb = wk + n * C_;
        for (int c = 0; c < C_; ++c) acc += ra[c] * rb[c];
        gtf[i2] = __float2bfloat16(acc);         // Brow[j][c] = G[c][j]
    } else if (b < 4224) {
        int i2 = (b - 4160) * 256 + tid;  // < 16384
        int f = i2 >> 9, r = i2 & 511;
        int lane = r >> 3, j = r & 7;
        int kt = f & 3, Nt = f >> 2;
        int k = kt * 32 + (lane >> 4) * 8 + j;
        int n = Nt * 16 + (lane & 15);
        wvtf[i2] = __float2bfloat16(wv[k * 128 + n]);   // Brow[c][j] = wv[j][c]
    } else if (b == 4224) {
        for (int i3 = tid; i3 < 2048; i3 += 256) {
            int f = i3 >> 9, r = i3 & 511;
            int lane = r >> 3, j = r & 7;
            int m = f * 16 + (lane & 15);
            int k = (lane >> 4) * 8 + j;
            tgf[i3] = (k < 25) ? __float2bfloat16(tg[m * 25 + k]) : __float2bfloat16(0.f);
        }
        if (tid < 128) {   // w[j] = wk_row_j . bq
            float acc = 0.f; const float* r = wk + tid * C_;
            for (int c = 0; c < C_; ++c) acc += r[c] * bq[c];
            ws[OFF_W + tid] = acc;
        }
        for (int idx = tid; idx < 64 * 64; idx += 256) {
            int s = idx >> 6, t = idx & 63;
            ws[OFF_PEDOT + idx] = pe[s*3]*pe[t*3] + pe[s*3+1]*pe[t*3+1] + pe[s*3+2]*pe[t*3+2];
        }
    } else {
        __shared__ float red[256];
        int bb = b - 4225;               // 0..63
        int i = bb >> 3, seg = bb & 7;
        int hl = tid & 63, part = tid >> 6;
        int h = seg * 64 + hl;
        const float* wcol = w1 + i * 65536 + h;
        float acc = 0.f;
        for (int c = part * 32; c < part * 32 + 32; ++c)
            acc += elnb[i * 128 + c] * wcol[c * 512];
        red[tid] = acc;
        __syncthreads();
        if (part == 0)
            ws[OFF_B1P + i * 512 + h] = red[hl] + red[hl + 64] + red[hl + 128] + red[hl + 192]
                                      + b1[i * 512 + h];
    }
}

// ---------------- kernA: fused grid-proj + LN + MFMA attention + l0 branch ----------------
// Conventions (verified): D[m][n] = sum_k A[m][k]*Brow[n][k]
//   A-frag: row lane&15, bytes kt*64 + quad*16 of a row-major K-contiguous row
//   B-frag: same pattern on Brow;  C/D: n = Ntbase + col, m = Mtbase + quad*4 + reg
__global__ __launch_bounds__(256) void kernA(
        const float* __restrict__ message, const float* __restrict__ ln1g,
        const float* __restrict__ ln1b, const float* __restrict__ bv,
        const float* __restrict__ ws_ro,
        const __hip_bfloat16* __restrict__ gtf, const __hip_bfloat16* __restrict__ wvtf,
        const __hip_bfloat16* __restrict__ tgf,
        const float* __restrict__ nlg, const float* __restrict__ nlb,
        const float* __restrict__ fcw, const float* __restrict__ fcb,
        __hip_bfloat16* __restrict__ nout, float* __restrict__ out) {
    __shared__ __align__(16) char sA[64 * 272];    // m rows [s][c]
    __shared__ __align__(16) char sB[64 * 272];    // (msg fp32 stage) -> z -> p -> out rows
    __shared__ __align__(16) char sC[128 * 144];   // (msgT bf16) -> sc fp32 [64][68] -> vT rows
    __shared__ __align__(16) float sStP[512];
    __shared__ __align__(16) float sSt2[128];
    __shared__ float sMw[64];
    __shared__ float sMsg0[128];                   // l0 branch input

    const int e = blockIdx.x, tid = threadIdx.x;
    const int w = tid >> 6, lane = tid & 63, quad = lane >> 4, col = lane & 15;

    // ---- 0a. stage msg fp32 (coalesced) into sB overlay; msg row 0 for l0 ----
    float* sMsgF = (float*)sB;
    for (int i = tid; i < 3200; i += 256) sMsgF[i] = message[(size_t)e * 3200 + i];
    if (tid < 128) sMsg0[tid] = message[(size_t)e * 3200 + tid];
    __syncthreads();   // S0a

    // ---- 0b. transpose+cvt+pad: msgT[c][l] bf16, row stride 80 B, l=25..31 zero ----
    char* sMt = sC;
    for (int i = tid; i < 4096; i += 256) {
        int c = i >> 5, l = i & 31;
        float v = (l < 25) ? sMsgF[l * 128 + c] : 0.f;
        *(__hip_bfloat16*)(sMt + c * 80 + l * 2) = __float2bfloat16(v);
    }
    __syncthreads();   // S0b

    // ---- 0c. g = to_grid @ msgT (K=32 MFMA); fused LN stats from registers ----
    floatx4 accG[4][2];
    {
        #pragma unroll
        for (int mt = 0; mt < 4; ++mt) { accG[mt][0] = (floatx4)0.f; accG[mt][1] = (floatx4)0.f; }
        bf16x8 a[4], b[2];
        #pragma unroll
        for (int mt = 0; mt < 4; ++mt) a[mt] = *(const bf16x8*)(tgf + mt * 512 + lane * 8);
        #pragma unroll
        for (int nt = 0; nt < 2; ++nt)
            b[nt] = *(const bf16x8*)(sMt + ((2 * w + nt) * 16 + col) * 80 + quad * 16);
        #pragma unroll
        for (int mt = 0; mt < 4; ++mt)
            #pragma unroll
            for (int nt = 0; nt < 2; ++nt)
                accG[mt][nt] = __builtin_amdgcn_mfma_f32_16x16x32_bf16(a[mt], b[nt], accG[mt][nt], 0, 0, 0);
    }
    #pragma unroll
    for (int mt = 0; mt < 4; ++mt)
        #pragma unroll
        for (int reg = 0; reg < 4; ++reg) {
            float v0 = accG[mt][0][reg], v1 = accG[mt][1][reg];
            float sm = v0 + v1, sq = v0 * v0 + v1 * v1;
            #pragma unroll
            for (int m = 1; m < 16; m <<= 1) {
                sm += __shfl_xor(sm, m, 64);
                sq += __shfl_xor(sq, m, 64);
            }
            if (col == 0) {
                int s = mt * 16 + quad * 4 + reg;
                sStP[(s * 4 + w) * 2]     = sm;
                sStP[(s * 4 + w) * 2 + 1] = sq;
            }
        }
    __syncthreads();   // Sg1
    if (tid < 64) {
        float sm = 0.f, sq = 0.f;
        #pragma unroll
        for (int k = 0; k < 4; ++k) {
            sm += sStP[(tid * 4 + k) * 2];
            sq += sStP[(tid * 4 + k) * 2 + 1];
        }
        float mean = sm * (1.f / 128.f);
        float rstd = rsqrtf(sq * (1.f / 128.f) - mean * mean + 1e-5f);
        sSt2[tid * 2] = mean; sSt2[tid * 2 + 1] = rstd;
    }
    __syncthreads();   // Sg2
    {
        float g1[2], b1v[2];
        #pragma unroll
        for (int nt = 0; nt < 2; ++nt) {
            int c = (2 * w + nt) * 16 + col;
            g1[nt] = ln1g[c]; b1v[nt] = ln1b[c];
        }
        #pragma unroll
        for (int mt = 0; mt < 4; ++mt)
            #pragma unroll
            for (int reg = 0; reg < 4; ++reg) {
                int s = mt * 16 + quad * 4 + reg;
                float mean = sSt2[s * 2], rstd = sSt2[s * 2 + 1];
                #pragma unroll
                for (int nt = 0; nt < 2; ++nt) {
                    int c = (2 * w + nt) * 16 + col;
                    ((__hip_bfloat16*)(sA + s * 272))[c] =
                        __float2bfloat16((accG[mt][nt][reg] - mean) * rstd * g1[nt] + b1v[nt]);
                }
            }
    }
    __syncthreads();   // S1 (m rows ready)

    // ---- 2. mw[t] = m_t . w ----
    {
        int t = tid >> 2, part = tid & 3;
        const __hip_bfloat16* mr = (const __hip_bfloat16*)(sA + t * 272) + part * 32;
        const float* wv_ = ws_ro + OFF_W + part * 32;
        float acc = 0.f;
        #pragma unroll
        for (int k = 0; k < 32; ++k) acc += __bfloat162float(mr[k]) * wv_[k];
        acc += __shfl_xor(acc, 1, 64);
        acc += __shfl_xor(acc, 2, 64);
        if (part == 0) sMw[t] = acc;
    }

    // ---- 3. z = m @ G (B-frags) ----
    {
        floatx4 accZ[4][2];
        #pragma unroll
        for (int mt = 0; mt < 4; ++mt) { accZ[mt][0] = (floatx4)0.f; accZ[mt][1] = (floatx4)0.f; }
        #pragma unroll
        for (int kt = 0; kt < 4; ++kt) {
            bf16x8 a[4], b[2];
            #pragma unroll
            for (int mt = 0; mt < 4; ++mt)
                a[mt] = *(const bf16x8*)(sA + (mt * 16 + col) * 272 + kt * 64 + quad * 16);
            #pragma unroll
            for (int nt = 0; nt < 2; ++nt)
                b[nt] = *(const bf16x8*)(gtf + ((2 * w + nt) * 4 + kt) * 512 + lane * 8);
            #pragma unroll
            for (int mt = 0; mt < 4; ++mt)
                #pragma unroll
                for (int nt = 0; nt < 2; ++nt)
                    accZ[mt][nt] = __builtin_amdgcn_mfma_f32_16x16x32_bf16(a[mt], b[nt], accZ[mt][nt], 0, 0, 0);
        }
        #pragma unroll
        for (int mt = 0; mt < 4; ++mt)
            #pragma unroll
            for (int nt = 0; nt < 2; ++nt) {
                int j = (2 * w + nt) * 16 + col;
                #pragma unroll
                for (int reg = 0; reg < 4; ++reg)
                    ((__hip_bfloat16*)(sB + (mt * 16 + quad * 4 + reg) * 272))[j] =
                        __float2bfloat16(accZ[mt][nt][reg]);
            }
    }
    __syncthreads();   // S2

    // ---- 4. sc = z @ m^T ----
    {
        floatx4 accS[4];
        #pragma unroll
        for (int mt = 0; mt < 4; ++mt) accS[mt] = (floatx4)0.f;
        #pragma unroll
        for (int kt = 0; kt < 4; ++kt) {
            bf16x8 a[4];
            #pragma unroll
            for (int mt = 0; mt < 4; ++mt)
                a[mt] = *(const bf16x8*)(sB + (mt * 16 + col) * 272 + kt * 64 + quad * 16);
            bf16x8 b = *(const bf16x8*)(sA + (w * 16 + col) * 272 + kt * 64 + quad * 16);
            #pragma unroll
            for (int mt = 0; mt < 4; ++mt)
                accS[mt] = __builtin_amdgcn_mfma_f32_16x16x32_bf16(a[mt], b, accS[mt], 0, 0, 0);
        }
        float* sc = (float*)sC;
        #pragma unroll
        for (int mt = 0; mt < 4; ++mt)
            #pragma unroll
            for (int reg = 0; reg < 4; ++reg)
                sc[(mt * 16 + quad * 4 + reg) * 68 + w * 16 + col] = accS[mt][reg];
    }
    __syncthreads();   // S3

    // ---- 5. softmax rows -> p rows bf16 ----
    {
        const float scale = 0.08737040566610379f;   // 1/sqrt(131)
        const float* sc = (const float*)sC;
        const float* pd = ws_ro + OFF_PEDOT;
        for (int r = 0; r < 16; ++r) {
            int s = w * 16 + r;
            float x = sc[s * 68 + lane] + sMw[lane] + pd[s * 64 + lane];
            float mx = x;
            #pragma unroll
            for (int m = 1; m < 64; m <<= 1) mx = fmaxf(mx, __shfl_xor(mx, m, 64));
            float p = __expf((x - mx) * scale);
            float sm = p;
            #pragma unroll
            for (int m = 1; m < 64; m <<= 1) sm += __shfl_xor(sm, m, 64);
            float rs = __builtin_amdgcn_rcpf(sm);
            ((__hip_bfloat16*)(sB + s * 272))[lane] = __float2bfloat16(p * rs);
        }
    }
    __syncthreads();   // S4

    // ---- 6. v = m @ Wv^T + bv -> vT rows [c][t] ----
    {
        floatx4 accV[4][2];
        #pragma unroll
        for (int mt = 0; mt < 4; ++mt) { accV[mt][0] = (floatx4)0.f; accV[mt][1] = (floatx4)0.f; }
        #pragma unroll
        for (int kt = 0; kt < 4; ++kt) {
            bf16x8 a[4], b[2];
            #pragma unroll
            for (int mt = 0; mt < 4; ++mt)
                a[mt] = *(const bf16x8*)(sA + (mt * 16 + col) * 272 + kt * 64 + quad * 16);
            #pragma unroll
            for (int nt = 0; nt < 2; ++nt)
                b[nt] = *(const bf16x8*)(wvtf + ((2 * w + nt) * 4 + kt) * 512 + lane * 8);
            #pragma unroll
            for (int mt = 0; mt < 4; ++mt)
                #pragma unroll
                for (int nt = 0; nt < 2; ++nt)
                    accV[mt][nt] = __builtin_amdgcn_mfma_f32_16x16x32_bf16(a[mt], b[nt], accV[mt][nt], 0, 0, 0);
        }
        #pragma unroll
        for (int nt = 0; nt < 2; ++nt) {
            int c = (2 * w + nt) * 16 + col;
            float bvv = bv[c];
            #pragma unroll
            for (int mt = 0; mt < 4; ++mt) {
                bf16x4 pk;
                #pragma unroll
                for (int reg = 0; reg < 4; ++reg)
                    pk[reg] = (__bf16)(accV[mt][nt][reg] + bvv);
                *(bf16x4*)(sC + c * 144 + (mt * 16 + quad * 4) * 2) = pk;
            }
        }
    }
    __syncthreads();   // S5

    // ---- 7. out = p @ vT ----
    floatx4 accO[4][2];
    #pragma unroll
    for (int mt = 0; mt < 4; ++mt) { accO[mt][0] = (floatx4)0.f; accO[mt][1] = (floatx4)0.f; }
    #pragma unroll
    for (int kt = 0; kt < 2; ++kt) {
        bf16x8 a[4], b[2];
        #pragma unroll
        for (int mt = 0; mt < 4; ++mt)
            a[mt] = *(const bf16x8*)(sB + (mt * 16 + col) * 272 + kt * 64 + quad * 16);
        #pragma unroll
        for (int nt = 0; nt < 2; ++nt)
            b[nt] = *(const bf16x8*)(sC + ((2 * w + nt) * 16 + col) * 144 + kt * 64 + quad * 16);
        #pragma unroll
        for (int mt = 0; mt < 4; ++mt)
            #pragma unroll
            for (int nt = 0; nt < 2; ++nt)
                accO[mt][nt] = __builtin_amdgcn_mfma_f32_16x16x32_bf16(a[mt], b[nt], accO[mt][nt], 0, 0, 0);
    }

    // ---- 8. LN partials ----
    #pragma unroll
    for (int mt = 0; mt < 4; ++mt)
        #pragma unroll
        for (int reg = 0; reg < 4; ++reg) {
            float v0 = accO[mt][0][reg], v1 = accO[mt][1][reg];
            float sm = v0 + v1, sq = v0 * v0 + v1 * v1;
            #pragma unroll
            for (int m = 1; m < 16; m <<= 1) {
                sm += __shfl_xor(sm, m, 64);
                sq += __shfl_xor(sq, m, 64);
            }
            if (col == 0) {
                int s = mt * 16 + quad * 4 + reg;
                sStP[(s * 4 + w) * 2]     = sm;
                sStP[(s * 4 + w) * 2 + 1] = sq;
            }
        }
    __syncthreads();   // S6
    if (tid < 64) {
        float sm = 0.f, sq = 0.f;
        #pragma unroll
        for (int k = 0; k < 4; ++k) {
            sm += sStP[(tid * 4 + k) * 2];
            sq += sStP[(tid * 4 + k) * 2 + 1];
        }
        float mean = sm * (1.f / 128.f);
        float rstd = rsqrtf(sq * (1.f / 128.f) - mean * mean + 1e-5f);
        sSt2[tid * 2] = mean; sSt2[tid * 2 + 1] = rstd;
    }
    __syncthreads();   // S7

    // ---- 9. normalize -> out rows bf16 ----
    #pragma unroll
    for (int mt = 0; mt < 4; ++mt)
        #pragma unroll
        for (int reg = 0; reg < 4; ++reg) {
            int s = mt * 16 + quad * 4 + reg;
            float mean = sSt2[s * 2], rstd = sSt2[s * 2 + 1];
            #pragma unroll
            for (int nt = 0; nt < 2; ++nt) {
                int c = (2 * w + nt) * 16 + col;
                ((__hip_bfloat16*)(sB + s * 272))[c] =
                    __float2bfloat16((accO[mt][nt][reg] - mean) * rstd);
            }
        }
    __syncthreads();   // S8

    // ---- 10. coalesced store nout ----
    for (int i = tid; i < 1024; i += 256) {
        int row = i >> 4, c16 = i & 15;
        bf16x8 v = *(const bf16x8*)(sB + row * 272 + c16 * 16);
        *(bf16x8*)(nout + (size_t)e * 8192 + row * 128 + c16 * 8) = v;
    }

    // ---- 11. l0 branch: LN -> Linear -> SiLU -> out row 0 ----
    if (tid < 64) {
        float x0 = sMsg0[tid], x1 = sMsg0[tid + 64];
        float sm = x0 + x1, sq = x0 * x0 + x1 * x1;
        #pragma unroll
        for (int m = 1; m < 64; m <<= 1) {
            sm += __shfl_xor(sm, m, 64);
            sq += __shfl_xor(sq, m, 64);
        }
        float mean = sm * (1.f / 128.f);
        float rstd = rsqrtf(sq * (1.f / 128.f) - mean * mean + 1e-5f);
        sMsg0[tid]      = (x0 - mean) * rstd * nlg[tid]      + nlb[tid];
        sMsg0[tid + 64] = (x1 - mean) * rstd * nlg[tid + 64] + nlb[tid + 64];
    }
    __syncthreads();   // S9
    {
        int c = tid & 127, jh = tid >> 7;
        float acc = 0.f;
        for (int j = jh * 64; j < jh * 64 + 64; ++j)
            acc += sMsg0[j] * fcw[j * 128 + c];
        sStP[tid] = acc;
    }
    __syncthreads();   // S10
    if (tid < 128) {
        float o = fcb[tid] + sStP[tid] + sStP[tid + 128];
        out[(size_t)e * 3200 + tid] = o * __builtin_amdgcn_rcpf(1.f + __expf(-o));
    }
}

// ---------------- kernC: 2 edges/block, X-frags in VGPRs, blob weight loads ----------------
__global__ __launch_bounds__(256, 2) void kernC(
        const __hip_bfloat16* __restrict__ nout_ro, const float* __restrict__ gate,
        const __hip_bfloat16* __restrict__ w1s, const __hip_bfloat16* __restrict__ w2s,
        const float* __restrict__ b1p, const float* __restrict__ b2,
        const float* __restrict__ fg, float* __restrict__ out) {

    __shared__ __align__(16) char sSb[128 * 272];   // S rows (both phases); epilogue overlay
    __shared__ float sGB2[2][128];
    float* sAcc = (float*)sSb;

    const int e0 = blockIdx.x * 2;
    const int tid = threadIdx.x;
    const int w = tid >> 6, lane = tid & 63;
    const int quad = lane >> 4, col = lane & 15;
    const int htB = (w >> 1) * 4;      // M-tile base
    const int stB = (w & 1) * 2;       // N-tile base

    // ---- X B-frags for both edges straight from global (64 VGPRs, loop-invariant) ----
    bf16x8 Xf[2][2][4];
    #pragma unroll
    for (int ph = 0; ph < 2; ++ph)
        #pragma unroll
        for (int nt = 0; nt < 2; ++nt)
            #pragma unroll
            for (int kt = 0; kt < 4; ++kt)
                Xf[ph][nt][kt] = *(const bf16x8*)(nout_ro +
                    (size_t)(e0 * 64 + ph * 64 + (stB + nt) * 16 + col) * 128 + kt * 32 + quad * 8);

    {   // gate-weighted b2 per edge
        int e_l = tid >> 7, c = tid & 127;
        float s = 0.f;
        #pragma unroll
        for (int ex = 0; ex < 8; ++ex) s += gate[(e0 + e_l) * 8 + ex] * b2[ex * 128 + c];
        sGB2[e_l][c] = s;
    }

    floatx4 accT[2][4][2];
    #pragma unroll
    for (int e = 0; e < 2; ++e)
        #pragma unroll
        for (int m = 0; m < 4; ++m)
            #pragma unroll
            for (int n2 = 0; n2 < 2; ++n2) accT[e][m][n2] = (floatx4)0.f;

    for (int it = 0; it < 32; ++it) {
        const int ex = it >> 2, hb = it & 3;
        const float gv0 = gate[e0 * 8 + ex];
        const float gv1 = gate[e0 * 8 + 8 + ex];

        // ---- w1 A-frags + bias, blob-loaded once for both phases ----
        bf16x8 a1[4][4];
        #pragma unroll
        for (int mt = 0; mt < 4; ++mt)
            #pragma unroll
            for (int kt = 0; kt < 4; ++kt)
                a1[mt][kt] = *(const bf16x8*)(w1s + (size_t)((ex*32 + hb*8 + htB + mt)*4 + kt)*512 + lane*8);
        float4 bias[4];
        #pragma unroll
        for (int mt = 0; mt < 4; ++mt)
            bias[mt] = *(const float4*)(b1p + ex * 512 + hb * 128 + (htB + mt) * 16 + quad * 4);

        #pragma unroll
        for (int ph = 0; ph < 2; ++ph) {
            const float gv = ph ? gv1 : gv0;
            floatx4 accP[4][2];
            #pragma unroll
            for (int mt = 0; mt < 4; ++mt)
                #pragma unroll
                for (int nt = 0; nt < 2; ++nt) {
                    accP[mt][nt][0] = bias[mt].x; accP[mt][nt][1] = bias[mt].y;
                    accP[mt][nt][2] = bias[mt].z; accP[mt][nt][3] = bias[mt].w;
                }
            #pragma unroll
            for (int kt = 0; kt < 4; ++kt)
                #pragma unroll
                for (int mt = 0; mt < 4; ++mt)
                    #pragma unroll
                    for (int nt = 0; nt < 2; ++nt)
                        accP[mt][nt] = __builtin_amdgcn_mfma_f32_16x16x32_bf16(a1[mt][kt], Xf[ph][nt][kt], accP[mt][nt], 0, 0, 0);
            // ---- silu * gate -> S rows ph*64+s ----
            #pragma unroll
            for (int mt = 0; mt < 4; ++mt) {
                int hl = (htB + mt) * 16 + quad * 4;
                #pragma unroll
                for (int nt = 0; nt < 2; ++nt) {
                    int nl = ph * 64 + (stB + nt) * 16 + col;
                    bf16x4 sv;
                    #pragma unroll
                    for (int r = 0; r < 4; ++r) {
                        float p = accP[mt][nt][r];
                        sv[r] = (__bf16)(gv * p * __builtin_amdgcn_rcpf(1.f + __expf(-p)));
                    }
                    *(bf16x4*)(sSb + nl * 272 + hl * 2) = sv;
                }
            }
        }
        __syncthreads();   // S for both phases ready

        // ---- w2 A-frags blob-loaded once ----
        bf16x8 a2[4][4];
        #pragma unroll
        for (int mt = 0; mt < 4; ++mt)
            #pragma unroll
            for (int kt = 0; kt < 4; ++kt)
                a2[mt][kt] = *(const bf16x8*)(w2s + (size_t)((ex*8 + htB + mt)*16 + hb*4 + kt)*512 + lane*8);
        #pragma unroll
        for (int ph = 0; ph < 2; ++ph) {
            #pragma unroll
            for (int kt = 0; kt < 4; ++kt) {
                bf16x8 b[2];
                #pragma unroll
                for (int nt = 0; nt < 2; ++nt) {
                    int nl = ph * 64 + (stB + nt) * 16 + col;
                    b[nt] = *(const bf16x8*)(sSb + nl * 272 + kt * 64 + quad * 16);
                }
                #pragma unroll
                for (int mt = 0; mt < 4; ++mt)
                    #pragma unroll
                    for (int nt = 0; nt < 2; ++nt)
                        accT[ph][mt][nt] = __builtin_amdgcn_mfma_f32_16x16x32_bf16(a2[mt][kt], b[nt], accT[ph][mt][nt], 0, 0, 0);
            }
        }
        __syncthreads();   // S region reusable
    }

    // ---- epilogue: per edge, acc -> sAcc, then out[l][c] = sum_s fg[l][s] * acc[s][c] ----
    for (int e = 0; e < 2; ++e) {
        #pragma unroll
        for (int mt = 0; mt < 4; ++mt) {
            int c = (htB + mt) * 16 + quad * 4;
            float4 gb = *(const float4*)(&sGB2[e][c]);
            #pragma unroll
            for (int nt = 0; nt < 2; ++nt) {
                int nl = (stB + nt) * 16 + col;
                float4 v;
                v.x = accT[e][mt][nt][0] + gb.x;
                v.y = accT[e][mt][nt][1] + gb.y;
                v.z = accT[e][mt][nt][2] + gb.z;
                v.w = accT[e][mt][nt][3] + gb.w;
                *(float4*)(sAcc + nl * 132 + c) = v;
            }
        }
        __syncthreads();
        for (int idx = tid; idx < 768; idx += 256) {
            int l = 1 + (idx >> 5);
            int c4 = (idx & 31) * 4;
            float4 a4 = {0.f, 0.f, 0.f, 0.f};
            const float* fgr = fg + l * 64;
            for (int s = 0; s < 64; ++s) {
                float f = fgr[s];
                const float* row = sAcc + s * 132 + c4;
                a4.x += f * row[0]; a4.y += f * row[1]; a4.z += f * row[2]; a4.w += f * row[3];
            }
            *(float4*)(out + (size_t)(e0 + e) * 3200 + l * 128 + c4) = a4;
        }
        __syncthreads();
    }
}

extern "C" void kernel_launch(void* const* d_in, const int* in_sizes, int n_in,
                              void* d_out, int out_size, void* d_ws, size_t ws_size,
                              hipStream_t stream) {
    (void)in_sizes; (void)n_in; (void)out_size; (void)ws_size;
    const float* message = (const float*)d_in[0];
    const float* gate    = (const float*)d_in[1];
    // d_in[2] = batch (unused by reference math)
    const float* ln1g = (const float*)d_in[3];
    const float* ln1b = (const float*)d_in[4];
    const float* wq   = (const float*)d_in[5];
    const float* bq   = (const float*)d_in[6];
    const float* wk   = (const float*)d_in[7];
    const float* bk   = (const float*)d_in[8];
    (void)bk;   // cancels in softmax (row-constant)
    const float* wv   = (const float*)d_in[9];
    const float* bv   = (const float*)d_in[10];
    const float* nlg  = (const float*)d_in[11];
    const float* nlb  = (const float*)d_in[12];
    const float* fcw  = (const float*)d_in[13];
    const float* fcb  = (const float*)d_in[14];
    const float* elng = (const float*)d_in[15];
    const float* elnb = (const float*)d_in[16];
    const float* w1   = (const float*)d_in[17];
    const float* b1   = (const float*)d_in[18];
    const float* w2   = (const float*)d_in[19];
    const float* b2   = (const float*)d_in[20];
    const float* tg   = (const float*)d_in[21];
    const float* fg   = (const float*)d_in[22];
    const float* pe   = (const float*)d_in[23];
    float* ws  = (float*)d_ws;
    float* out = (float*)d_out;
    __hip_bfloat16* gtfp = (__hip_bfloat16*)(ws + OFF_GTF);
    __hip_bfloat16* wvtf = (__hip_bfloat16*)(ws + OFF_WVTF);
    __hip_bfloat16* tgf  = (__hip_bfloat16*)(ws + OFF_TGF);
    __hip_bfloat16* w1s  = (__hip_bfloat16*)(ws + OFF_W1S);
    __hip_bfloat16* w2s  = (__hip_bfloat16*)(ws + OFF_W2S);
    __hip_bfloat16* nout = (__hip_bfloat16*)(ws + OFF_NOUT);

    prepAll<<<dim3(4289), dim3(256), 0, stream>>>(wq, bq, wk, wv, tg, pe, elng, elnb,
                                                  w1, b1, w2, w1s, w2s, gtfp, wvtf, tgf, ws);
    kernA<<<dim3(E_), dim3(256), 0, stream>>>(message, ln1g, ln1b, bv, ws, gtfp, wvtf, tgf,
                                              nlg, nlb, fcw, fcb, nout, out);
    kernC<<<dim3(E_ / 2), dim3(256), 0, stream>>>(nout, gate, w1s, w2s,
                                                  ws + OFF_B1P, b2, fg, out);
}

// Round 10
// 333.631 us; speedup vs baseline: 1.4614x; 1.2024x over previous
//
#include <hip/hip_runtime.h>
#include <hip/hip_bf16.h>

#define E_ 1024
#define L_ 25
#define S_ 64
#define C_ 128
#define H_ 512
#define NEXP_ 8

// workspace float offsets
#define OFF_W     0         // 128 (wk @ bq fold, for mw[t])
#define OFF_PEDOT 128       // 64*64 -> 4224
#define OFF_B1P   4224      // 8*512 -> 8320
#define OFF_GTF   8320      // 16384 bf16 (G frags) = 8192 fl -> 16512
#define OFF_WVTF  16512     // 16384 bf16 (Wv^T frags) -> 24704
#define OFF_TGF   24704     // 2048 bf16 (to_grid A-frags) = 1024 fl -> 25728
#define OFF_W1S   25728     // 524288 bf16 = 262144 fl -> 287872
#define OFF_W2S   287872    // 524288 bf16 -> 550016
#define OFF_NOUT  550016    // 1024*64*128 bf16 = 4194304 fl -> 4744320 (~19 MB)

typedef float floatx4 __attribute__((ext_vector_type(4)));
typedef __bf16 bf16x8 __attribute__((ext_vector_type(8)));
typedef __bf16 bf16x4 __attribute__((ext_vector_type(4)));

// ---------------- prepAll: every weight transform in ONE launch ----------------
__global__ void prepAll(const float* __restrict__ wq, const float* __restrict__ bq,
                        const float* __restrict__ wk, const float* __restrict__ wv,
                        const float* __restrict__ tg, const float* __restrict__ pe,
                        const float* __restrict__ elng, const float* __restrict__ elnb,
                        const float* __restrict__ w1, const float* __restrict__ b1,
                        const float* __restrict__ w2,
                        __hip_bfloat16* __restrict__ w1s, __hip_bfloat16* __restrict__ w2s,
                        __hip_bfloat16* __restrict__ gtf, __hip_bfloat16* __restrict__ wvtf,
                        __hip_bfloat16* __restrict__ tgf, float* __restrict__ ws) {
    const int b = blockIdx.x, tid = threadIdx.x;
    if (b < 2048) {
        int idx = b * 256 + tid;          // < 524288
        int f = idx >> 9, r = idx & 511;
        int lane = r >> 3, j = r & 7;
        int kt = f & 3, htg = (f >> 2) & 31, ex = f >> 7;
        int c = kt * 32 + (lane >> 4) * 8 + j;
        int h = htg * 16 + (lane & 15);
        w1s[idx] = __float2bfloat16(elng[ex * 128 + c] * w1[ex * 65536 + c * 512 + h]);
    } else if (b < 4096) {
        int i2 = (b - 2048) * 256 + tid;  // < 524288
        int f = i2 >> 9, r = i2 & 511;
        int lane = r >> 3, j = r & 7;
        int ktg = f & 15, ctg = (f >> 4) & 7, ex = f >> 7;
        int h = ktg * 32 + (lane >> 4) * 8 + j;
        int c = ctg * 16 + (lane & 15);
        w2s[i2] = __float2bfloat16(w2[ex * 65536 + h * 128 + c]);
    } else if (b < 4160) {
        int i2 = (b - 4096) * 256 + tid;  // < 16384
        int f = i2 >> 9, r = i2 & 511;
        int lane = r >> 3, j = r & 7;
        int kt = f & 3, Nt = f >> 2;
        int k = kt * 32 + (lane >> 4) * 8 + j;   // row of wq
        int n = Nt * 16 + (lane & 15);           // row of wk
        float acc = 0.f;
        const float* ra = wq + k * C_;
        const float* rb = wk + n * C_;
        for (int c = 0; c < C_; ++c) acc += ra[c] * rb[c];
        gtf[i2] = __float2bfloat16(acc);         // Brow[j][c] = G[c][j]
    } else if (b < 4224) {
        int i2 = (b - 4160) * 256 + tid;  // < 16384
        int f = i2 >> 9, r = i2 & 511;
        int lane = r >> 3, j = r & 7;
        int kt = f & 3, Nt = f >> 2;
        int k = kt * 32 + (lane >> 4) * 8 + j;
        int n = Nt * 16 + (lane & 15);
        wvtf[i2] = __float2bfloat16(wv[k * 128 + n]);   // Brow[c][j] = wv[j][c]
    } else if (b == 4224) {
        for (int i3 = tid; i3 < 2048; i3 += 256) {
            int f = i3 >> 9, r = i3 & 511;
            int lane = r >> 3, j = r & 7;
            int m = f * 16 + (lane & 15);
            int k = (lane >> 4) * 8 + j;
            tgf[i3] = (k < 25) ? __float2bfloat16(tg[m * 25 + k]) : __float2bfloat16(0.f);
        }
        if (tid < 128) {   // w[j] = wk_row_j . bq
            float acc = 0.f; const float* r = wk + tid * C_;
            for (int c = 0; c < C_; ++c) acc += r[c] * bq[c];
            ws[OFF_W + tid] = acc;
        }
        for (int idx = tid; idx < 64 * 64; idx += 256) {
            int s = idx >> 6, t = idx & 63;
            ws[OFF_PEDOT + idx] = pe[s*3]*pe[t*3] + pe[s*3+1]*pe[t*3+1] + pe[s*3+2]*pe[t*3+2];
        }
    } else {
        __shared__ float red[256];
        int bb = b - 4225;               // 0..63
        int i = bb >> 3, seg = bb & 7;
        int hl = tid & 63, part = tid >> 6;
        int h = seg * 64 + hl;
        const float* wcol = w1 + i * 65536 + h;
        float acc = 0.f;
        for (int c = part * 32; c < part * 32 + 32; ++c)
            acc += elnb[i * 128 + c] * wcol[c * 512];
        red[tid] = acc;
        __syncthreads();
        if (part == 0)
            ws[OFF_B1P + i * 512 + h] = red[hl] + red[hl + 64] + red[hl + 128] + red[hl + 192]
                                      + b1[i * 512 + h];
    }
}

// ---------------- kernA: fused grid-proj + LN + MFMA attention + l0 branch ----------------
// Conventions (verified): D[m][n] = sum_k A[m][k]*Brow[n][k]
//   A-frag: row lane&15, bytes kt*64 + quad*16 of a row-major K-contiguous row
//   B-frag: same pattern on Brow;  C/D: n = Ntbase + col, m = Mtbase + quad*4 + reg
__global__ __launch_bounds__(256) void kernA(
        const float* __restrict__ message, const float* __restrict__ ln1g,
        const float* __restrict__ ln1b, const float* __restrict__ bv,
        const float* __restrict__ ws_ro,
        const __hip_bfloat16* __restrict__ gtf, const __hip_bfloat16* __restrict__ wvtf,
        const __hip_bfloat16* __restrict__ tgf,
        const float* __restrict__ nlg, const float* __restrict__ nlb,
        const float* __restrict__ fcw, const float* __restrict__ fcb,
        __hip_bfloat16* __restrict__ nout, float* __restrict__ out) {
    __shared__ __align__(16) char sA[64 * 272];    // m rows [s][c]
    __shared__ __align__(16) char sB[64 * 272];    // (msg fp32 stage) -> z -> p -> out rows
    __shared__ __align__(16) char sC[128 * 144];   // (msgT bf16) -> sc fp32 [64][68] -> vT rows
    __shared__ __align__(16) float sStP[512];
    __shared__ __align__(16) float sSt2[128];
    __shared__ float sMw[64];
    __shared__ float sMsg0[128];                   // l0 branch input

    const int e = blockIdx.x, tid = threadIdx.x;
    const int w = tid >> 6, lane = tid & 63, quad = lane >> 4, col = lane & 15;

    // ---- 0a. stage msg fp32 (coalesced) into sB overlay; msg row 0 for l0 ----
    float* sMsgF = (float*)sB;
    for (int i = tid; i < 3200; i += 256) sMsgF[i] = message[(size_t)e * 3200 + i];
    if (tid < 128) sMsg0[tid] = message[(size_t)e * 3200 + tid];
    __syncthreads();   // S0a

    // ---- 0b. transpose+cvt+pad: msgT[c][l] bf16, row stride 80 B, l=25..31 zero ----
    char* sMt = sC;
    for (int i = tid; i < 4096; i += 256) {
        int c = i >> 5, l = i & 31;
        float v = (l < 25) ? sMsgF[l * 128 + c] : 0.f;
        *(__hip_bfloat16*)(sMt + c * 80 + l * 2) = __float2bfloat16(v);
    }
    __syncthreads();   // S0b

    // ---- 0c. g = to_grid @ msgT (K=32 MFMA); fused LN stats from registers ----
    floatx4 accG[4][2];
    {
        #pragma unroll
        for (int mt = 0; mt < 4; ++mt) { accG[mt][0] = (floatx4)0.f; accG[mt][1] = (floatx4)0.f; }
        bf16x8 a[4], b[2];
        #pragma unroll
        for (int mt = 0; mt < 4; ++mt) a[mt] = *(const bf16x8*)(tgf + mt * 512 + lane * 8);
        #pragma unroll
        for (int nt = 0; nt < 2; ++nt)
            b[nt] = *(const bf16x8*)(sMt + ((2 * w + nt) * 16 + col) * 80 + quad * 16);
        #pragma unroll
        for (int mt = 0; mt < 4; ++mt)
            #pragma unroll
            for (int nt = 0; nt < 2; ++nt)
                accG[mt][nt] = __builtin_amdgcn_mfma_f32_16x16x32_bf16(a[mt], b[nt], accG[mt][nt], 0, 0, 0);
    }
    #pragma unroll
    for (int mt = 0; mt < 4; ++mt)
        #pragma unroll
        for (int reg = 0; reg < 4; ++reg) {
            float v0 = accG[mt][0][reg], v1 = accG[mt][1][reg];
            float sm = v0 + v1, sq = v0 * v0 + v1 * v1;
            #pragma unroll
            for (int m = 1; m < 16; m <<= 1) {
                sm += __shfl_xor(sm, m, 64);
                sq += __shfl_xor(sq, m, 64);
            }
            if (col == 0) {
                int s = mt * 16 + quad * 4 + reg;
                sStP[(s * 4 + w) * 2]     = sm;
                sStP[(s * 4 + w) * 2 + 1] = sq;
            }
        }
    __syncthreads();   // Sg1
    if (tid < 64) {
        float sm = 0.f, sq = 0.f;
        #pragma unroll
        for (int k = 0; k < 4; ++k) {
            sm += sStP[(tid * 4 + k) * 2];
            sq += sStP[(tid * 4 + k) * 2 + 1];
        }
        float mean = sm * (1.f / 128.f);
        float rstd = rsqrtf(sq * (1.f / 128.f) - mean * mean + 1e-5f);
        sSt2[tid * 2] = mean; sSt2[tid * 2 + 1] = rstd;
    }
    __syncthreads();   // Sg2
    {
        float g1[2], b1v[2];
        #pragma unroll
        for (int nt = 0; nt < 2; ++nt) {
            int c = (2 * w + nt) * 16 + col;
            g1[nt] = ln1g[c]; b1v[nt] = ln1b[c];
        }
        #pragma unroll
        for (int mt = 0; mt < 4; ++mt)
            #pragma unroll
            for (int reg = 0; reg < 4; ++reg) {
                int s = mt * 16 + quad * 4 + reg;
                float mean = sSt2[s * 2], rstd = sSt2[s * 2 + 1];
                #pragma unroll
                for (int nt = 0; nt < 2; ++nt) {
                    int c = (2 * w + nt) * 16 + col;
                    ((__hip_bfloat16*)(sA + s * 272))[c] =
                        __float2bfloat16((accG[mt][nt][reg] - mean) * rstd * g1[nt] + b1v[nt]);
                }
            }
    }
    __syncthreads();   // S1 (m rows ready)

    // ---- 2. mw[t] = m_t . w ----
    {
        int t = tid >> 2, part = tid & 3;
        const __hip_bfloat16* mr = (const __hip_bfloat16*)(sA + t * 272) + part * 32;
        const float* wv_ = ws_ro + OFF_W + part * 32;
        float acc = 0.f;
        #pragma unroll
        for (int k = 0; k < 32; ++k) acc += __bfloat162float(mr[k]) * wv_[k];
        acc += __shfl_xor(acc, 1, 64);
        acc += __shfl_xor(acc, 2, 64);
        if (part == 0) sMw[t] = acc;
    }

    // ---- 3. z = m @ G (B-frags) ----
    {
        floatx4 accZ[4][2];
        #pragma unroll
        for (int mt = 0; mt < 4; ++mt) { accZ[mt][0] = (floatx4)0.f; accZ[mt][1] = (floatx4)0.f; }
        #pragma unroll
        for (int kt = 0; kt < 4; ++kt) {
            bf16x8 a[4], b[2];
            #pragma unroll
            for (int mt = 0; mt < 4; ++mt)
                a[mt] = *(const bf16x8*)(sA + (mt * 16 + col) * 272 + kt * 64 + quad * 16);
            #pragma unroll
            for (int nt = 0; nt < 2; ++nt)
                b[nt] = *(const bf16x8*)(gtf + ((2 * w + nt) * 4 + kt) * 512 + lane * 8);
            #pragma unroll
            for (int mt = 0; mt < 4; ++mt)
                #pragma unroll
                for (int nt = 0; nt < 2; ++nt)
                    accZ[mt][nt] = __builtin_amdgcn_mfma_f32_16x16x32_bf16(a[mt], b[nt], accZ[mt][nt], 0, 0, 0);
        }
        #pragma unroll
        for (int mt = 0; mt < 4; ++mt)
            #pragma unroll
            for (int nt = 0; nt < 2; ++nt) {
                int j = (2 * w + nt) * 16 + col;
                #pragma unroll
                for (int reg = 0; reg < 4; ++reg)
                    ((__hip_bfloat16*)(sB + (mt * 16 + quad * 4 + reg) * 272))[j] =
                        __float2bfloat16(accZ[mt][nt][reg]);
            }
    }
    __syncthreads();   // S2

    // ---- 4. sc = z @ m^T ----
    {
        floatx4 accS[4];
        #pragma unroll
        for (int mt = 0; mt < 4; ++mt) accS[mt] = (floatx4)0.f;
        #pragma unroll
        for (int kt = 0; kt < 4; ++kt) {
            bf16x8 a[4];
            #pragma unroll
            for (int mt = 0; mt < 4; ++mt)
                a[mt] = *(const bf16x8*)(sB + (mt * 16 + col) * 272 + kt * 64 + quad * 16);
            bf16x8 b = *(const bf16x8*)(sA + (w * 16 + col) * 272 + kt * 64 + quad * 16);
            #pragma unroll
            for (int mt = 0; mt < 4; ++mt)
                accS[mt] = __builtin_amdgcn_mfma_f32_16x16x32_bf16(a[mt], b, accS[mt], 0, 0, 0);
        }
        float* sc = (float*)sC;
        #pragma unroll
        for (int mt = 0; mt < 4; ++mt)
            #pragma unroll
            for (int reg = 0; reg < 4; ++reg)
                sc[(mt * 16 + quad * 4 + reg) * 68 + w * 16 + col] = accS[mt][reg];
    }
    __syncthreads();   // S3

    // ---- 5. softmax rows -> p rows bf16 ----
    {
        const float scale = 0.08737040566610379f;   // 1/sqrt(131)
        const float* sc = (const float*)sC;
        const float* pd = ws_ro + OFF_PEDOT;
        for (int r = 0; r < 16; ++r) {
            int s = w * 16 + r;
            float x = sc[s * 68 + lane] + sMw[lane] + pd[s * 64 + lane];
            float mx = x;
            #pragma unroll
            for (int m = 1; m < 64; m <<= 1) mx = fmaxf(mx, __shfl_xor(mx, m, 64));
            float p = __expf((x - mx) * scale);
            float sm = p;
            #pragma unroll
            for (int m = 1; m < 64; m <<= 1) sm += __shfl_xor(sm, m, 64);
            float rs = __builtin_amdgcn_rcpf(sm);
            ((__hip_bfloat16*)(sB + s * 272))[lane] = __float2bfloat16(p * rs);
        }
    }
    __syncthreads();   // S4

    // ---- 6. v = m @ Wv^T + bv -> vT rows [c][t] ----
    {
        floatx4 accV[4][2];
        #pragma unroll
        for (int mt = 0; mt < 4; ++mt) { accV[mt][0] = (floatx4)0.f; accV[mt][1] = (floatx4)0.f; }
        #pragma unroll
        for (int kt = 0; kt < 4; ++kt) {
            bf16x8 a[4], b[2];
            #pragma unroll
            for (int mt = 0; mt < 4; ++mt)
                a[mt] = *(const bf16x8*)(sA + (mt * 16 + col) * 272 + kt * 64 + quad * 16);
            #pragma unroll
            for (int nt = 0; nt < 2; ++nt)
                b[nt] = *(const bf16x8*)(wvtf + ((2 * w + nt) * 4 + kt) * 512 + lane * 8);
            #pragma unroll
            for (int mt = 0; mt < 4; ++mt)
                #pragma unroll
                for (int nt = 0; nt < 2; ++nt)
                    accV[mt][nt] = __builtin_amdgcn_mfma_f32_16x16x32_bf16(a[mt], b[nt], accV[mt][nt], 0, 0, 0);
        }
        #pragma unroll
        for (int nt = 0; nt < 2; ++nt) {
            int c = (2 * w + nt) * 16 + col;
            float bvv = bv[c];
            #pragma unroll
            for (int mt = 0; mt < 4; ++mt) {
                bf16x4 pk;
                #pragma unroll
                for (int reg = 0; reg < 4; ++reg)
                    pk[reg] = (__bf16)(accV[mt][nt][reg] + bvv);
                *(bf16x4*)(sC + c * 144 + (mt * 16 + quad * 4) * 2) = pk;
            }
        }
    }
    __syncthreads();   // S5

    // ---- 7. out = p @ vT ----
    floatx4 accO[4][2];
    #pragma unroll
    for (int mt = 0; mt < 4; ++mt) { accO[mt][0] = (floatx4)0.f; accO[mt][1] = (floatx4)0.f; }
    #pragma unroll
    for (int kt = 0; kt < 2; ++kt) {
        bf16x8 a[4], b[2];
        #pragma unroll
        for (int mt = 0; mt < 4; ++mt)
            a[mt] = *(const bf16x8*)(sB + (mt * 16 + col) * 272 + kt * 64 + quad * 16);
        #pragma unroll
        for (int nt = 0; nt < 2; ++nt)
            b[nt] = *(const bf16x8*)(sC + ((2 * w + nt) * 16 + col) * 144 + kt * 64 + quad * 16);
        #pragma unroll
        for (int mt = 0; mt < 4; ++mt)
            #pragma unroll
            for (int nt = 0; nt < 2; ++nt)
                accO[mt][nt] = __builtin_amdgcn_mfma_f32_16x16x32_bf16(a[mt], b[nt], accO[mt][nt], 0, 0, 0);
    }

    // ---- 8. LN partials ----
    #pragma unroll
    for (int mt = 0; mt < 4; ++mt)
        #pragma unroll
        for (int reg = 0; reg < 4; ++reg) {
            float v0 = accO[mt][0][reg], v1 = accO[mt][1][reg];
            float sm = v0 + v1, sq = v0 * v0 + v1 * v1;
            #pragma unroll
            for (int m = 1; m < 16; m <<= 1) {
                sm += __shfl_xor(sm, m, 64);
                sq += __shfl_xor(sq, m, 64);
            }
            if (col == 0) {
                int s = mt * 16 + quad * 4 + reg;
                sStP[(s * 4 + w) * 2]     = sm;
                sStP[(s * 4 + w) * 2 + 1] = sq;
            }
        }
    __syncthreads();   // S6
    if (tid < 64) {
        float sm = 0.f, sq = 0.f;
        #pragma unroll
        for (int k = 0; k < 4; ++k) {
            sm += sStP[(tid * 4 + k) * 2];
            sq += sStP[(tid * 4 + k) * 2 + 1];
        }
        float mean = sm * (1.f / 128.f);
        float rstd = rsqrtf(sq * (1.f / 128.f) - mean * mean + 1e-5f);
        sSt2[tid * 2] = mean; sSt2[tid * 2 + 1] = rstd;
    }
    __syncthreads();   // S7

    // ---- 9. normalize -> out rows bf16 ----
    #pragma unroll
    for (int mt = 0; mt < 4; ++mt)
        #pragma unroll
        for (int reg = 0; reg < 4; ++reg) {
            int s = mt * 16 + quad * 4 + reg;
            float mean = sSt2[s * 2], rstd = sSt2[s * 2 + 1];
            #pragma unroll
            for (int nt = 0; nt < 2; ++nt) {
                int c = (2 * w + nt) * 16 + col;
                ((__hip_bfloat16*)(sB + s * 272))[c] =
                    __float2bfloat16((accO[mt][nt][reg] - mean) * rstd);
            }
        }
    __syncthreads();   // S8

    // ---- 10. coalesced store nout ----
    for (int i = tid; i < 1024; i += 256) {
        int row = i >> 4, c16 = i & 15;
        bf16x8 v = *(const bf16x8*)(sB + row * 272 + c16 * 16);
        *(bf16x8*)(nout + (size_t)e * 8192 + row * 128 + c16 * 8) = v;
    }

    // ---- 11. l0 branch: LN -> Linear -> SiLU -> out row 0 ----
    if (tid < 64) {
        float x0 = sMsg0[tid], x1 = sMsg0[tid + 64];
        float sm = x0 + x1, sq = x0 * x0 + x1 * x1;
        #pragma unroll
        for (int m = 1; m < 64; m <<= 1) {
            sm += __shfl_xor(sm, m, 64);
            sq += __shfl_xor(sq, m, 64);
        }
        float mean = sm * (1.f / 128.f);
        float rstd = rsqrtf(sq * (1.f / 128.f) - mean * mean + 1e-5f);
        sMsg0[tid]      = (x0 - mean) * rstd * nlg[tid]      + nlb[tid];
        sMsg0[tid + 64] = (x1 - mean) * rstd * nlg[tid + 64] + nlb[tid + 64];
    }
    __syncthreads();   // S9
    {
        int c = tid & 127, jh = tid >> 7;
        float acc = 0.f;
        for (int j = jh * 64; j < jh * 64 + 64; ++j)
            acc += sMsg0[j] * fcw[j * 128 + c];
        sStP[tid] = acc;
    }
    __syncthreads();   // S10
    if (tid < 128) {
        float o = fcb[tid] + sStP[tid] + sStP[tid + 128];
        out[(size_t)e * 3200 + tid] = o * __builtin_amdgcn_rcpf(1.f + __expf(-o));
    }
}

// ---------------- kernC: round-6 structure (2 edges/block, LDS X, blob weight loads) ----------------
__global__ __launch_bounds__(256, 2) void kernC(
        const __hip_bfloat16* __restrict__ nout_ro, const float* __restrict__ gate,
        const __hip_bfloat16* __restrict__ w1s, const __hip_bfloat16* __restrict__ w2s,
        const float* __restrict__ b1p, const float* __restrict__ b2,
        const float* __restrict__ fg, float* __restrict__ out) {

    __shared__ __align__(16) char smem[128 * 272 + 128 * 272];   // sX + sS(both ph)
    __shared__ float sGB2[2][128];
    char* sXb = smem;                 // X[n=128][c=128] bf16, row stride 272 B
    char* sSb = smem + 128 * 272;     // S[n=128][h=128] bf16 (rows ph*64+s)
    float* sAcc = (float*)smem;       // epilogue overlay

    const int e0 = blockIdx.x * 2;
    const int tid = threadIdx.x;
    const int w = tid >> 6, lane = tid & 63;
    const int quad = lane >> 4, col = lane & 15;
    const int htB = (w >> 1) * 4;      // M-tile base
    const int stB = (w & 1) * 2;       // N-tile base

    // ---- stage X: pure bf16 copy ----
    for (int i = tid; i < 2048; i += 256) {
        int n = i >> 4, c16 = i & 15;
        bf16x8 v = *(const bf16x8*)(nout_ro + (size_t)(e0 * 64 + n) * 128 + c16 * 8);
        *(bf16x8*)(sXb + n * 272 + c16 * 16) = v;
    }
    {   // gate-weighted b2 per edge
        int e_l = tid >> 7, c = tid & 127;
        float s = 0.f;
        #pragma unroll
        for (int ex = 0; ex < 8; ++ex) s += gate[(e0 + e_l) * 8 + ex] * b2[ex * 128 + c];
        sGB2[e_l][c] = s;
    }
    __syncthreads();

    floatx4 accT[2][4][2];
    #pragma unroll
    for (int e = 0; e < 2; ++e)
        #pragma unroll
        for (int m = 0; m < 4; ++m)
            #pragma unroll
            for (int n2 = 0; n2 < 2; ++n2) accT[e][m][n2] = (floatx4)0.f;

    for (int ex = 0; ex < NEXP_; ++ex) {
        const float gv0 = gate[e0 * 8 + ex];
        const float gv1 = gate[e0 * 8 + 8 + ex];
        for (int hb = 0; hb < 4; ++hb) {
            // ---- w1 A-frags + bias, loaded ONCE for both phases ----
            bf16x8 a1[4][4];
            #pragma unroll
            for (int mt = 0; mt < 4; ++mt)
                #pragma unroll
                for (int kt = 0; kt < 4; ++kt)
                    a1[mt][kt] = *(const bf16x8*)(w1s + (size_t)((ex*32 + hb*8 + htB + mt)*4 + kt)*512 + lane*8);
            float4 bias[4];
            #pragma unroll
            for (int mt = 0; mt < 4; ++mt)
                bias[mt] = *(const float4*)(b1p + ex * 512 + hb * 128 + (htB + mt) * 16 + quad * 4);

            #pragma unroll
            for (int ph = 0; ph < 2; ++ph) {
                const float gv = ph ? gv1 : gv0;
                floatx4 accP[4][2];
                #pragma unroll
                for (int mt = 0; mt < 4; ++mt)
                    #pragma unroll
                    for (int nt = 0; nt < 2; ++nt) {
                        accP[mt][nt][0] = bias[mt].x; accP[mt][nt][1] = bias[mt].y;
                        accP[mt][nt][2] = bias[mt].z; accP[mt][nt][3] = bias[mt].w;
                    }
                #pragma unroll
                for (int kt = 0; kt < 4; ++kt) {
                    bf16x8 b[2];
                    #pragma unroll
                    for (int nt = 0; nt < 2; ++nt) {
                        int n = ph * 64 + (stB + nt) * 16 + col;
                        b[nt] = *(const bf16x8*)(sXb + n * 272 + kt * 64 + quad * 16);
                    }
                    #pragma unroll
                    for (int mt = 0; mt < 4; ++mt)
                        #pragma unroll
                        for (int nt = 0; nt < 2; ++nt)
                            accP[mt][nt] = __builtin_amdgcn_mfma_f32_16x16x32_bf16(a1[mt][kt], b[nt], accP[mt][nt], 0, 0, 0);
                }
                // ---- silu * gate -> S rows ph*64+s ----
                #pragma unroll
                for (int mt = 0; mt < 4; ++mt) {
                    int hl = (htB + mt) * 16 + quad * 4;
                    #pragma unroll
                    for (int nt = 0; nt < 2; ++nt) {
                        int nl = ph * 64 + (stB + nt) * 16 + col;
                        bf16x4 sv;
                        #pragma unroll
                        for (int r = 0; r < 4; ++r) {
                            float p = accP[mt][nt][r];
                            sv[r] = (__bf16)(gv * p * __builtin_amdgcn_rcpf(1.f + __expf(-p)));
                        }
                        *(bf16x4*)(sSb + nl * 272 + hl * 2) = sv;
                    }
                }
            }
            __syncthreads();   // S for both phases ready

            // ---- w2 A-frags loaded ONCE ----
            bf16x8 a2[4][4];
            #pragma unroll
            for (int mt = 0; mt < 4; ++mt)
                #pragma unroll
                for (int kt = 0; kt < 4; ++kt)
                    a2[mt][kt] = *(const bf16x8*)(w2s + (size_t)((ex*8 + htB + mt)*16 + hb*4 + kt)*512 + lane*8);
            #pragma unroll
            for (int ph = 0; ph < 2; ++ph) {
                #pragma unroll
                for (int kt = 0; kt < 4; ++kt) {
                    bf16x8 b[2];
                    #pragma unroll
                    for (int nt = 0; nt < 2; ++nt) {
                        int nl = ph * 64 + (stB + nt) * 16 + col;
                        b[nt] = *(const bf16x8*)(sSb + nl * 272 + kt * 64 + quad * 16);
                    }
                    #pragma unroll
                    for (int mt = 0; mt < 4; ++mt)
                        #pragma unroll
                        for (int nt = 0; nt < 2; ++nt)
                            accT[ph][mt][nt] = __builtin_amdgcn_mfma_f32_16x16x32_bf16(a2[mt][kt], b[nt], accT[ph][mt][nt], 0, 0, 0);
                }
            }
            __syncthreads();   // S region reusable
        }
    }

    // ---- epilogue: per edge, acc -> sAcc, then out[l][c] = sum_s fg[l][s] * acc[s][c] ----
    for (int e = 0; e < 2; ++e) {
        #pragma unroll
        for (int mt = 0; mt < 4; ++mt) {
            int c = (htB + mt) * 16 + quad * 4;
            float4 gb = *(const float4*)(&sGB2[e][c]);
            #pragma unroll
            for (int nt = 0; nt < 2; ++nt) {
                int nl = (stB + nt) * 16 + col;
                float4 v;
                v.x = accT[e][mt][nt][0] + gb.x;
                v.y = accT[e][mt][nt][1] + gb.y;
                v.z = accT[e][mt][nt][2] + gb.z;
                v.w = accT[e][mt][nt][3] + gb.w;
                *(float4*)(sAcc + nl * 132 + c) = v;
            }
        }
        __syncthreads();
        for (int idx = tid; idx < 768; idx += 256) {
            int l = 1 + (idx >> 5);
            int c4 = (idx & 31) * 4;
            float4 a4 = {0.f, 0.f, 0.f, 0.f};
            const float* fgr = fg + l * 64;
            for (int s = 0; s < 64; ++s) {
                float f = fgr[s];
                const float* row = sAcc + s * 132 + c4;
                a4.x += f * row[0]; a4.y += f * row[1]; a4.z += f * row[2]; a4.w += f * row[3];
            }
            *(float4*)(out + (size_t)(e0 + e) * 3200 + l * 128 + c4) = a4;
        }
        __syncthreads();
    }
}

extern "C" void kernel_launch(void* const* d_in, const int* in_sizes, int n_in,
                              void* d_out, int out_size, void* d_ws, size_t ws_size,
                              hipStream_t stream) {
    (void)in_sizes; (void)n_in; (void)out_size; (void)ws_size;
    const float* message = (const float*)d_in[0];
    const float* gate    = (const float*)d_in[1];
    // d_in[2] = batch (unused by reference math)
    const float* ln1g = (const float*)d_in[3];
    const float* ln1b = (const float*)d_in[4];
    const float* wq   = (const float*)d_in[5];
    const float* bq   = (const float*)d_in[6];
    const float* wk   = (const float*)d_in[7];
    const float* bk   = (const float*)d_in[8];
    (void)bk;   // cancels in softmax (row-constant)
    const float* wv   = (const float*)d_in[9];
    const float* bv   = (const float*)d_in[10];
    const float* nlg  = (const float*)d_in[11];
    const float* nlb  = (const float*)d_in[12];
    const float* fcw  = (const float*)d_in[13];
    const float* fcb  = (const float*)d_in[14];
    const float* elng = (const float*)d_in[15];
    const float* elnb = (const float*)d_in[16];
    const float* w1   = (const float*)d_in[17];
    const float* b1   = (const float*)d_in[18];
    const float* w2   = (const float*)d_in[19];
    const float* b2   = (const float*)d_in[20];
    const float* tg   = (const float*)d_in[21];
    const float* fg   = (const float*)d_in[22];
    const float* pe   = (const float*)d_in[23];
    float* ws  = (float*)d_ws;
    float* out = (float*)d_out;
    __hip_bfloat16* gtfp = (__hip_bfloat16*)(ws + OFF_GTF);
    __hip_bfloat16* wvtf = (__hip_bfloat16*)(ws + OFF_WVTF);
    __hip_bfloat16* tgf  = (__hip_bfloat16*)(ws + OFF_TGF);
    __hip_bfloat16* w1s  = (__hip_bfloat16*)(ws + OFF_W1S);
    __hip_bfloat16* w2s  = (__hip_bfloat16*)(ws + OFF_W2S);
    __hip_bfloat16* nout = (__hip_bfloat16*)(ws + OFF_NOUT);

    prepAll<<<dim3(4289), dim3(256), 0, stream>>>(wq, bq, wk, wv, tg, pe, elng, elnb,
                                                  w1, b1, w2, w1s, w2s, gtfp, wvtf, tgf, ws);
    kernA<<<dim3(E_), dim3(256), 0, stream>>>(message, ln1g, ln1b, bv, ws, gtfp, wvtf, tgf,
                                              nlg, nlb, fcw, fcb, nout, out);
    kernC<<<dim3(E_ / 2), dim3(256), 0, stream>>>(nout, gate, w1s, w2s,
                                                  ws + OFF_B1P, b2, fg, out);
}